// Round 8
// baseline (855.999 us; speedup 1.0000x reference)
//
#include <hip/hip_runtime.h>

typedef unsigned short u16;
typedef unsigned int   u32;
typedef __attribute__((ext_vector_type(8))) short  short8;
typedef __attribute__((ext_vector_type(8))) u16    ushort8;
typedef __attribute__((ext_vector_type(4))) u16    ushort4v;
typedef __attribute__((ext_vector_type(4))) float  f32x4;

#define AS1 __attribute__((address_space(1)))
#define AS3 __attribute__((address_space(3)))

// counters are padded: one u32 per 64B line (stride 16 u32)
#define CSTRIDE 16
// per-(block,row,slot) LDS candidate list capacity (Poisson(~2.3), P(any overflow)~6e-4, drop cost ~1e-3)
#define CAPB 16

__device__ __forceinline__ float bf2f(u16 u) {
    union { u32 i; float f; } x; x.i = ((u32)u) << 16; return x.f;
}
__device__ __forceinline__ u16 f2bf(float f) {
    union { float f; u32 i; } x; x.f = f;
    u32 r = x.i + 0x7fffu + ((x.i >> 16) & 1u);
    return (u16)(r >> 16);
}

// ---------------------------------------------------------------- prep kernels

__global__ __launch_bounds__(256) void k_transpose_cast(
    const float* __restrict__ src, u16* __restrict__ dst, int R, int C)
{
    int i = blockIdx.x * 256 + threadIdx.x;
    if (i >= R * C) return;
    int r = i / C, c = i - r * C;
    dst[(size_t)c * R + r] = f2bf(src[i]);
}

__global__ __launch_bounds__(256) void k_cast8(
    const float* __restrict__ src, u16* __restrict__ dst)
{
    size_t i = ((size_t)blockIdx.x * 256 + threadIdx.x) * 8;
    float4 a = *(const float4*)(src + i);
    float4 b = *(const float4*)(src + i + 4);
    ushort8 o;
    o[0] = f2bf(a.x); o[1] = f2bf(a.y); o[2] = f2bf(a.z); o[3] = f2bf(a.w);
    o[4] = f2bf(b.x); o[5] = f2bf(b.y); o[6] = f2bf(b.z); o[7] = f2bf(b.w);
    *(ushort8*)(dst + i) = o;
}

// one wave per key vector (256 floats); 4 keys per block
__global__ __launch_bounds__(256) void k_norm_keys(
    const float* __restrict__ keys, u16* __restrict__ kn)
{
    int key  = blockIdx.x * 4 + (threadIdx.x >> 6);
    int lane = threadIdx.x & 63;
    const float* kp = keys + (size_t)key * 256 + lane * 4;
    float4 v = *(const float4*)kp;
    float ss = v.x * v.x + v.y * v.y + v.z * v.z + v.w * v.w;
#pragma unroll
    for (int o = 32; o; o >>= 1) ss += __shfl_xor(ss, o);
    float sc = 1.0f / sqrtf(ss);
    ushort4v o4;
    o4[0] = f2bf(v.x * sc); o4[1] = f2bf(v.y * sc);
    o4[2] = f2bf(v.z * sc); o4[3] = f2bf(v.w * sc);
    *(ushort4v*)(kn + (size_t)key * 256 + lane * 4) = o4;
}

// one wave per q row: rn[row] = |q_row|  (from bf16 q)
__global__ __launch_bounds__(256) void k_rownorm(
    const u16* __restrict__ q, float* __restrict__ rn)
{
    int row  = blockIdx.x * 4 + (threadIdx.x >> 6);
    int lane = threadIdx.x & 63;
    ushort4v u = *(const ushort4v*)(q + (size_t)row * 256 + lane * 4);
    float a = bf2f(u[0]), b = bf2f(u[1]), c = bf2f(u[2]), d = bf2f(u[3]);
    float ss = a * a + b * b + c * c + d * d;
#pragma unroll
    for (int o = 32; o; o >>= 1) ss += __shfl_xor(ss, o);
    if (lane == 0) rn[row] = sqrtf(ss);
}

// ---------------------------------------------------------------- bf16 NT GEMM
// C(MxN) = A(MxK) * B(NxK)^T ; A,B bf16 row-major (K contiguous).
// EPI 1: +bias, store bf16. EPI 2: +bias, store f32.
template<int EPI>
__global__ __launch_bounds__(256) void gemm_nt(
    const short* __restrict__ A, const short* __restrict__ B,
    void* __restrict__ Cp, const float* __restrict__ bias,
    int M, int N, int K, int ldc)
{
    __shared__ __align__(16) short lA[128 * 32];
    __shared__ __align__(16) short lB[128 * 32];
    const int t  = threadIdx.x;
    const int m0 = blockIdx.y << 7, n0 = blockIdx.x << 7;
    const int w  = t >> 6, lane = t & 63;
    const int wr = (w >> 1) << 6, wc = (w & 1) << 6;
    const int qr = lane & 15, qh = lane >> 4;

    f32x4 acc[4][4];
#pragma unroll
    for (int i = 0; i < 4; ++i)
#pragma unroll
        for (int j = 0; j < 4; ++j) acc[i][j] = (f32x4){0.f, 0.f, 0.f, 0.f};

    const short* ga0 = A + (size_t)(m0 + (t >> 2)) * K + (t & 3) * 8;
    const short* ga1 = ga0 + (size_t)64 * K;
    const short* gb0 = B + (size_t)(n0 + (t >> 2)) * K + (t & 3) * 8;
    const short* gb1 = gb0 + (size_t)64 * K;
    char* lAb = (char*)lA + w * 1024;
    char* lBb = (char*)lB + w * 1024;

    for (int k0 = 0; k0 < K; k0 += 32) {
        __builtin_amdgcn_global_load_lds((const AS1 void*)(ga0 + k0), (AS3 void*)lAb,          16, 0, 0);
        __builtin_amdgcn_global_load_lds((const AS1 void*)(ga1 + k0), (AS3 void*)(lAb + 4096), 16, 0, 0);
        __builtin_amdgcn_global_load_lds((const AS1 void*)(gb0 + k0), (AS3 void*)lBb,          16, 0, 0);
        __builtin_amdgcn_global_load_lds((const AS1 void*)(gb1 + k0), (AS3 void*)(lBb + 4096), 16, 0, 0);
        __syncthreads();
        short8 af[4], bfr[4];
#pragma unroll
        for (int i = 0; i < 4; ++i) af[i]  = *(const short8*)&lA[(wr + i * 16 + qr) * 32 + qh * 8];
#pragma unroll
        for (int i = 0; i < 4; ++i) bfr[i] = *(const short8*)&lB[(wc + i * 16 + qr) * 32 + qh * 8];
#pragma unroll
        for (int mi = 0; mi < 4; ++mi)
#pragma unroll
            for (int ni = 0; ni < 4; ++ni)
                acc[mi][ni] = __builtin_amdgcn_mfma_f32_16x16x32_bf16(af[mi], bfr[ni], acc[mi][ni], 0, 0, 0);
        __syncthreads();
    }

#pragma unroll
    for (int mi = 0; mi < 4; ++mi)
#pragma unroll
        for (int ni = 0; ni < 4; ++ni) {
            const int col = n0 + wc + ni * 16 + qr;
            float bv = bias[col];
            f32x4 a = acc[mi][ni];
#pragma unroll
            for (int j = 0; j < 4; ++j) {
                const int row = m0 + wr + mi * 16 + qh * 4 + j;
                float v = a[j] + bv;
                if (EPI == 2) ((float*)Cp)[(size_t)row * ldc + col] = v;
                else          ((u16*)Cp)[(size_t)row * ldc + col]  = f2bf(v);
            }
        }
}

// ---------------------------------------------------------------- score GEMM
// Slot-fused, 3-buffer 2-deep pipeline with counted vmcnt and STATIC buffer
// parity (loop unrolled by 3). Per step g (parity P):
//   ds_read buf[P] ; lgkmcnt(0)+bar ; STAGE(g+2)->buf[(P+2)%3] ; MFMA ;
//   [slot epilogue] ; vmcnt(4)+bar            (vmcnt never 0 mid-loop)
// No sched_barrier order-pinning (m141) — compiler schedules freely within
// phases; asm memory clobbers provide the required ordering.
__global__ __launch_bounds__(256) void gemm_scores(
    const short* __restrict__ A, const short* __restrict__ Bk,
    const float* __restrict__ rn, u32* __restrict__ cnt,
    float2* __restrict__ cand, int cap, float cmul)
{
    __shared__ __align__(16) short lA3[3][128 * 32];
    __shared__ __align__(16) short lB3[3][128 * 32];
    __shared__ u32    lcnt[128];
    __shared__ float2 lbuf[128][CAPB];

    const int t  = threadIdx.x;
    const int m0 = blockIdx.y << 7, n0 = blockIdx.x << 7;
    const int w  = t >> 6, lane = t & 63;
    const int wr = (w >> 1) << 6, wc = (w & 1) << 6;
    const int qr = lane & 15, qh = lane >> 4;
    const int K  = 256;

    const short* ga0 = A + (size_t)(m0 + (t >> 2)) * K + (t & 3) * 8;
    const short* ga1 = ga0 + (size_t)64 * K;
    const short* gbb = Bk + (size_t)(n0 + (t >> 2)) * K + (t & 3) * 8;

    f32x4 acc[4][4];
#pragma unroll
    for (int i = 0; i < 4; ++i)
#pragma unroll
        for (int j = 0; j < 4; ++j) acc[i][j] = (f32x4){0.f, 0.f, 0.f, 0.f};

#define STAGE(g, PB) do {                                                            \
    const int k0_ = ((g) & 7) * 32;                                                  \
    const short* gb0_ = gbb + (size_t)((g) >> 3) * (16384 * 256) + k0_;              \
    char* la_ = (char*)&lA3[PB][0] + w * 1024;                                       \
    char* lb_ = (char*)&lB3[PB][0] + w * 1024;                                       \
    __builtin_amdgcn_global_load_lds((const AS1 void*)(ga0 + k0_),      (AS3 void*)la_,          16, 0, 0); \
    __builtin_amdgcn_global_load_lds((const AS1 void*)(ga1 + k0_),      (AS3 void*)(la_ + 4096), 16, 0, 0); \
    __builtin_amdgcn_global_load_lds((const AS1 void*)gb0_,             (AS3 void*)lb_,          16, 0, 0); \
    __builtin_amdgcn_global_load_lds((const AS1 void*)(gb0_ + 64*256),  (AS3 void*)(lb_ + 4096), 16, 0, 0); \
} while (0)

#define EPILOGUE(g) do {                                                             \
    const int sl_ = (g) >> 3;                                                        \
    u32*    cnts_  = cnt  + (size_t)sl_ * 4096 * CSTRIDE;                            \
    float2* cands_ = cand + (size_t)sl_ * 4096 * cap;                                \
    if (t < 128) lcnt[t] = 0;                                                        \
    asm volatile("s_waitcnt lgkmcnt(0)" ::: "memory");                               \
    __builtin_amdgcn_s_barrier();                                                    \
    _Pragma("unroll")                                                                \
    for (int mi = 0; mi < 4; ++mi) {                                                 \
        const int rbase = wr + mi * 16 + qh * 4;                                     \
        float thrj[4];                                                               \
        _Pragma("unroll")                                                            \
        for (int j = 0; j < 4; ++j) thrj[j] = cmul * rn[m0 + rbase + j];             \
        _Pragma("unroll")                                                            \
        for (int ni = 0; ni < 4; ++ni) {                                             \
            const int col = n0 + wc + ni * 16 + qr;                                  \
            f32x4 a = acc[mi][ni];                                                   \
            _Pragma("unroll")                                                        \
            for (int j = 0; j < 4; ++j) {                                            \
                float v = a[j];                                                      \
                if (v > thrj[j]) {                                                   \
                    const int rl = rbase + j;                                        \
                    u32 p = atomicAdd(&lcnt[rl], 1u);                                \
                    if (p < CAPB) lbuf[rl][p] = make_float2(v, __uint_as_float((u32)col)); \
                }                                                                    \
            }                                                                        \
        }                                                                            \
    }                                                                                \
    asm volatile("s_waitcnt lgkmcnt(0)" ::: "memory");                               \
    __builtin_amdgcn_s_barrier();                                                    \
    if (t < 128) {                                                                   \
        int c_ = (int)lcnt[t];                                                       \
        if (c_ > CAPB) c_ = CAPB;                                                    \
        if (c_ > 0) {                                                                \
            const int row_ = m0 + t;                                                 \
            u32 base_ = atomicAdd(&cnts_[(size_t)row_ * CSTRIDE], (u32)c_);          \
            float2* dst_ = cands_ + (size_t)row_ * cap;                              \
            for (int i_ = 0; i_ < c_; ++i_) {                                        \
                u32 p_ = base_ + (u32)i_;                                            \
                if (p_ < (u32)cap) dst_[p_] = lbuf[t][i_];                           \
            }                                                                        \
        }                                                                            \
    }                                                                                \
    _Pragma("unroll")                                                                \
    for (int i_ = 0; i_ < 4; ++i_)                                                   \
        _Pragma("unroll")                                                            \
        for (int j_ = 0; j_ < 4; ++j_) acc[i_][j_] = (f32x4){0.f, 0.f, 0.f, 0.f};    \
} while (0)

#define KSTEP(g, P, PN) do {                                                         \
    short8 af[4], bfr[4];                                                            \
    _Pragma("unroll")                                                                \
    for (int i = 0; i < 4; ++i) af[i]  = *(const short8*)&lA3[P][(wr + i*16 + qr)*32 + qh*8]; \
    _Pragma("unroll")                                                                \
    for (int i = 0; i < 4; ++i) bfr[i] = *(const short8*)&lB3[P][(wc + i*16 + qr)*32 + qh*8]; \
    asm volatile("s_waitcnt lgkmcnt(0)" ::: "memory");                               \
    __builtin_amdgcn_s_barrier();                                                    \
    if ((g) + 2 < 32) STAGE((g) + 2, PN);                                            \
    _Pragma("unroll")                                                                \
    for (int mi = 0; mi < 4; ++mi)                                                   \
        _Pragma("unroll")                                                            \
        for (int ni = 0; ni < 4; ++ni)                                               \
            acc[mi][ni] = __builtin_amdgcn_mfma_f32_16x16x32_bf16(af[mi], bfr[ni], acc[mi][ni], 0, 0, 0); \
    if (((g) & 7) == 7) EPILOGUE(g);                                                 \
    if ((g) + 2 < 32) asm volatile("s_waitcnt vmcnt(4)" ::: "memory");               \
    else              asm volatile("s_waitcnt vmcnt(0)" ::: "memory");               \
    __builtin_amdgcn_s_barrier();                                                    \
} while (0)

    // prologue: fill pipeline 2 deep; vmcnt(4) -> STAGE(0) complete
    STAGE(0, 0);
    STAGE(1, 1);
    asm volatile("s_waitcnt vmcnt(4)" ::: "memory");
    __builtin_amdgcn_s_barrier();

    for (int gg = 0; gg < 30; gg += 3) {
        KSTEP(gg,     0, 2);
        KSTEP(gg + 1, 1, 0);
        KSTEP(gg + 2, 2, 1);
    }
    KSTEP(30, 0, 2);
    KSTEP(31, 1, 0);

#undef KSTEP
#undef EPILOGUE
#undef STAGE
}

// ---------------------------------------------------------------- select+gather
// One WAVE per (slot,row). Reads the row's candidate list (~300 f32 entries),
// exact top-32 by 32x wave-argmax with (val desc, idx asc) order — identical
// semantics to jax.lax.top_k on the f32 scores. Softmax, fused weighted gather
// of values + residual.
__global__ __launch_bounds__(256) void k_select(
    const u32* __restrict__ cnt, const float2* __restrict__ cand, int cap,
    const void* __restrict__ vtab,    // value tables, all slots (bf16 or f32)
    const float* __restrict__ res,    // BS x 512
    float* __restrict__ out,          // BS x 4 x 512
    int useBf)
{
    __shared__ float2 cbuf[4][512];
    __shared__ float  topw[4][32];
    __shared__ int    topi[4][32];

    const int t = threadIdx.x;
    const int w = t >> 6, lane = t & 63;
    const int wid = blockIdx.x * 4 + w;          // 0..16383
    const int s   = wid >> 12;                   // slot
    const int row = wid & 4095;                  // batch row
    const int g   = s * 4096 + row;

    int c = (int)cnt[(size_t)g * CSTRIDE];
    if (c > cap) c = cap;
    const float2* cp = cand + (size_t)g * cap;
    for (int i = lane; i < c; i += 64) cbuf[w][i] = cp[i];

    // ---- 32x wave-argmax (val desc, idx asc), wave-synchronous
    for (int k = 0; k < 32; ++k) {
        float bv = -3.0e38f; int bi = 0x7fffffff; int bp = -1;
        for (int i = lane; i < c; i += 64) {
            float2 e = cbuf[w][i];
            float v = e.x; int id = (int)__float_as_uint(e.y);
            if (v > bv || (v == bv && id < bi)) { bv = v; bi = id; bp = i; }
        }
#pragma unroll
        for (int o = 32; o; o >>= 1) {
            float ov = __shfl_xor(bv, o);
            int   oi = __shfl_xor(bi, o);
            int   op = __shfl_xor(bp, o);
            if (ov > bv || (ov == bv && oi < bi)) { bv = ov; bi = oi; bp = op; }
        }
        if (lane == 0) {
            topw[w][k] = bv;
            topi[w][k] = (bi == 0x7fffffff) ? 0 : bi;
            if (bp >= 0) cbuf[w][bp].x = -3.0e38f;   // remove winner
        }
    }

    // ---- softmax over top-32 (lanes 0..31; k=0 holds the max)
    if (lane < 32) {
        float v  = topw[w][lane];
        float mx = topw[w][0];
        float e  = expf(v - mx);
        float sum = e;
#pragma unroll
        for (int o = 16; o; o >>= 1) sum += __shfl_xor(sum, o, 32);
        topw[w][lane] = e / sum;
    }

    // ---- fused gather + residual: lane owns 8 contiguous outputs
    const int v0 = lane * 8;
    float a[8];
    {
        float4 r0v = *(const float4*)(res + (size_t)row * 512 + v0);
        float4 r1v = *(const float4*)(res + (size_t)row * 512 + v0 + 4);
        a[0] = r0v.x; a[1] = r0v.y; a[2] = r0v.z; a[3] = r0v.w;
        a[4] = r1v.x; a[5] = r1v.y; a[6] = r1v.z; a[7] = r1v.w;
    }
    if (useBf) {
        const u16* vt = (const u16*)vtab + (size_t)s * 16384 * 512;
#pragma unroll 8
        for (int k = 0; k < 32; ++k) {
            float w2 = topw[w][k];
            ushort8 u = *(const ushort8*)(vt + (size_t)topi[w][k] * 512 + v0);
#pragma unroll
            for (int i = 0; i < 8; ++i) a[i] += w2 * bf2f(u[i]);
        }
    } else {
        const float* vt = (const float*)vtab + (size_t)s * 16384 * 512;
#pragma unroll 4
        for (int k = 0; k < 32; ++k) {
            float w2 = topw[w][k];
            const float* vp = vt + (size_t)topi[w][k] * 512 + v0;
            float4 u0 = *(const float4*)vp;
            float4 u1 = *(const float4*)(vp + 4);
            a[0] += w2 * u0.x; a[1] += w2 * u0.y; a[2] += w2 * u0.z; a[3] += w2 * u0.w;
            a[4] += w2 * u1.x; a[5] += w2 * u1.y; a[6] += w2 * u1.z; a[7] += w2 * u1.w;
        }
    }
    float* op = out + ((size_t)row * 4 + s) * 512 + v0;
    *(float4*)op       = (float4){a[0], a[1], a[2], a[3]};
    *(float4*)(op + 4) = (float4){a[4], a[5], a[6], a[7]};
}

// ---------------------------------------------------------------- host

extern "C" void kernel_launch(void* const* d_in, const int* in_sizes, int n_in,
                              void* d_out, int out_size, void* d_ws, size_t ws_size,
                              hipStream_t stream)
{
    const float* x    = (const float*)d_in[0];
    const float* Wq   = (const float*)d_in[1];
    const float* bq   = (const float*)d_in[2];
    const float* keys = (const float*)d_in[3];
    const float* vals = (const float*)d_in[4];
    const float* Wr   = (const float*)d_in[5];
    const float* br   = (const float*)d_in[6];
    float* out = (float*)d_out;
    char*  ws  = (char*)d_ws;

    constexpr int BS = 4096, D = 512, KD = 256, VD = 512, S = 4, NK = 16384;

    size_t pos = 0;
    auto take = [&](size_t bytes) -> size_t {
        size_t p = (pos + 255) & ~(size_t)255; pos = p + bytes; return p;
    };
    size_t o_xbf = take((size_t)BS * D * 2);
    size_t o_wqt = take((size_t)KD * D * 2);
    size_t o_wrt = take((size_t)VD * KD * 2);
    size_t o_qbf = take((size_t)BS * KD * 2);
    size_t o_res = take((size_t)BS * VD * 4);
    size_t o_kn  = take((size_t)S * NK * KD * 2);
    size_t o_rn  = take((size_t)BS * 4);
    size_t o_cnt = take((size_t)S * BS * CSTRIDE * 4);   // 64B-padded counters
    size_t core_end = pos;

    // tiers: [vbf?] + candidate capacity / threshold constant
    const size_t vbf_b = (size_t)S * NK * VD * 2;                  // 64 MB
    auto cand_b = [&](int cap) { return (size_t)S * BS * cap * 8; };
    bool use_vbf = false; int cap = 192; float cmul = 2.45f / 16.0f;
    if (core_end + vbf_b + cand_b(512) + 1024 <= ws_size) {
        use_vbf = true;  cap = 512; cmul = 2.1f / 16.0f;
    } else if (core_end + cand_b(512) + 1024 <= ws_size) {
        use_vbf = false; cap = 512; cmul = 2.1f / 16.0f;
    } else if (core_end + cand_b(320) + 1024 <= ws_size) {
        use_vbf = false; cap = 320; cmul = 2.3f / 16.0f;
    }
    size_t o_vbf  = use_vbf ? take(vbf_b) : 0;
    size_t o_cand = take(cand_b(cap));

    // zero per-row candidate counters (graph-capturable memset node)
    hipMemsetAsync(ws + o_cnt, 0, (size_t)S * BS * CSTRIDE * 4, stream);

    // prep
    k_transpose_cast<<<(D * KD + 255) / 256, 256, 0, stream>>>(Wq, (u16*)(ws + o_wqt), D, KD);
    k_transpose_cast<<<(KD * VD + 255) / 256, 256, 0, stream>>>(Wr, (u16*)(ws + o_wrt), KD, VD);
    k_cast8<<<(BS * D) / 2048, 256, 0, stream>>>(x, (u16*)(ws + o_xbf));
    if (use_vbf)
        k_cast8<<<(S * NK * VD) / 2048, 256, 0, stream>>>(vals, (u16*)(ws + o_vbf));
    k_norm_keys<<<(S * NK) / 4, 256, 0, stream>>>(keys, (u16*)(ws + o_kn));

    // q = x @ Wq + bq  (bf16 out)
    gemm_nt<1><<<dim3(KD / 128, BS / 128), 256, 0, stream>>>(
        (const short*)(ws + o_xbf), (const short*)(ws + o_wqt),
        ws + o_qbf, bq, BS, KD, D, KD);
    // row norms of q
    k_rownorm<<<BS / 4, 256, 0, stream>>>((const u16*)(ws + o_qbf), (float*)(ws + o_rn));
    // res = q @ Wr + br  (f32 out)
    gemm_nt<2><<<dim3(VD / 128, BS / 128), 256, 0, stream>>>(
        (const short*)(ws + o_qbf), (const short*)(ws + o_wrt),
        ws + o_res, br, BS, VD, KD, VD);

    // scores: slot-fused pipelined dispatch; epilogue filters into candidate lists
    gemm_scores<<<dim3(NK / 128, BS / 128), 256, 0, stream>>>(
        (const short*)(ws + o_qbf), (const short*)(ws + o_kn),
        (const float*)(ws + o_rn), (u32*)(ws + o_cnt),
        (float2*)(ws + o_cand), cap, cmul);

    // exact top-32 + softmax + gather + residual, all slots in one dispatch
    const void* vtab = use_vbf ? (const void*)(ws + o_vbf) : (const void*)vals;
    k_select<<<(S * BS) / 4, 256, 0, stream>>>(
        (const u32*)(ws + o_cnt), (const float2*)(ws + o_cand), cap,
        vtab, (const float*)(ws + o_res), out, use_vbf ? 1 : 0);
}

// Round 9
// 552.360 us; speedup vs baseline: 1.5497x; 1.5497x over previous
//
#include <hip/hip_runtime.h>

typedef unsigned short u16;
typedef unsigned int   u32;
typedef __attribute__((ext_vector_type(8))) short  short8;
typedef __attribute__((ext_vector_type(8))) u16    ushort8;
typedef __attribute__((ext_vector_type(4))) u16    ushort4v;
typedef __attribute__((ext_vector_type(4))) float  f32x4;

#define AS1 __attribute__((address_space(1)))
#define AS3 __attribute__((address_space(3)))

// counters are padded: one u32 per 64B line (stride 16 u32)
#define CSTRIDE 16
// per-(block,row,slot) LDS candidate list capacity (Poisson(~2.3), P(>16)~1e-11)
#define CAPB 16

__device__ __forceinline__ float bf2f(u16 u) {
    union { u32 i; float f; } x; x.i = ((u32)u) << 16; return x.f;
}
__device__ __forceinline__ u16 f2bf(float f) {
    union { float f; u32 i; } x; x.f = f;
    u32 r = x.i + 0x7fffu + ((x.i >> 16) & 1u);
    return (u16)(r >> 16);
}

// ---------------------------------------------------------------- prep kernels

__global__ __launch_bounds__(256) void k_transpose_cast(
    const float* __restrict__ src, u16* __restrict__ dst, int R, int C)
{
    int i = blockIdx.x * 256 + threadIdx.x;
    if (i >= R * C) return;
    int r = i / C, c = i - r * C;
    dst[(size_t)c * R + r] = f2bf(src[i]);
}

__global__ __launch_bounds__(256) void k_cast8(
    const float* __restrict__ src, u16* __restrict__ dst)
{
    size_t i = ((size_t)blockIdx.x * 256 + threadIdx.x) * 8;
    float4 a = *(const float4*)(src + i);
    float4 b = *(const float4*)(src + i + 4);
    ushort8 o;
    o[0] = f2bf(a.x); o[1] = f2bf(a.y); o[2] = f2bf(a.z); o[3] = f2bf(a.w);
    o[4] = f2bf(b.x); o[5] = f2bf(b.y); o[6] = f2bf(b.z); o[7] = f2bf(b.w);
    *(ushort8*)(dst + i) = o;
}

// one wave per key vector (256 floats); 4 keys per block
__global__ __launch_bounds__(256) void k_norm_keys(
    const float* __restrict__ keys, u16* __restrict__ kn)
{
    int key  = blockIdx.x * 4 + (threadIdx.x >> 6);
    int lane = threadIdx.x & 63;
    const float* kp = keys + (size_t)key * 256 + lane * 4;
    float4 v = *(const float4*)kp;
    float ss = v.x * v.x + v.y * v.y + v.z * v.z + v.w * v.w;
#pragma unroll
    for (int o = 32; o; o >>= 1) ss += __shfl_xor(ss, o);
    float sc = 1.0f / sqrtf(ss);
    ushort4v o4;
    o4[0] = f2bf(v.x * sc); o4[1] = f2bf(v.y * sc);
    o4[2] = f2bf(v.z * sc); o4[3] = f2bf(v.w * sc);
    *(ushort4v*)(kn + (size_t)key * 256 + lane * 4) = o4;
}

// one wave per q row: rn[row] = |q_row|  (from bf16 q)
__global__ __launch_bounds__(256) void k_rownorm(
    const u16* __restrict__ q, float* __restrict__ rn)
{
    int row  = blockIdx.x * 4 + (threadIdx.x >> 6);
    int lane = threadIdx.x & 63;
    ushort4v u = *(const ushort4v*)(q + (size_t)row * 256 + lane * 4);
    float a = bf2f(u[0]), b = bf2f(u[1]), c = bf2f(u[2]), d = bf2f(u[3]);
    float ss = a * a + b * b + c * c + d * d;
#pragma unroll
    for (int o = 32; o; o >>= 1) ss += __shfl_xor(ss, o);
    if (lane == 0) rn[row] = sqrtf(ss);
}

// ---------------------------------------------------------------- bf16 NT GEMM
// C(MxN) = A(MxK) * B(NxK)^T ; A,B bf16 row-major (K contiguous).
// EPI 1: +bias, store bf16. EPI 2: +bias, store f32.
template<int EPI>
__global__ __launch_bounds__(256) void gemm_nt(
    const short* __restrict__ A, const short* __restrict__ B,
    void* __restrict__ Cp, const float* __restrict__ bias,
    int M, int N, int K, int ldc)
{
    __shared__ __align__(16) short lA[128 * 32];
    __shared__ __align__(16) short lB[128 * 32];
    const int t  = threadIdx.x;
    const int m0 = blockIdx.y << 7, n0 = blockIdx.x << 7;
    const int w  = t >> 6, lane = t & 63;
    const int wr = (w >> 1) << 6, wc = (w & 1) << 6;
    const int qr = lane & 15, qh = lane >> 4;

    f32x4 acc[4][4];
#pragma unroll
    for (int i = 0; i < 4; ++i)
#pragma unroll
        for (int j = 0; j < 4; ++j) acc[i][j] = (f32x4){0.f, 0.f, 0.f, 0.f};

    const short* ga0 = A + (size_t)(m0 + (t >> 2)) * K + (t & 3) * 8;
    const short* ga1 = ga0 + (size_t)64 * K;
    const short* gb0 = B + (size_t)(n0 + (t >> 2)) * K + (t & 3) * 8;
    const short* gb1 = gb0 + (size_t)64 * K;
    char* lAb = (char*)lA + w * 1024;
    char* lBb = (char*)lB + w * 1024;

    for (int k0 = 0; k0 < K; k0 += 32) {
        __builtin_amdgcn_global_load_lds((const AS1 void*)(ga0 + k0), (AS3 void*)lAb,          16, 0, 0);
        __builtin_amdgcn_global_load_lds((const AS1 void*)(ga1 + k0), (AS3 void*)(lAb + 4096), 16, 0, 0);
        __builtin_amdgcn_global_load_lds((const AS1 void*)(gb0 + k0), (AS3 void*)lBb,          16, 0, 0);
        __builtin_amdgcn_global_load_lds((const AS1 void*)(gb1 + k0), (AS3 void*)(lBb + 4096), 16, 0, 0);
        __syncthreads();
        short8 af[4], bfr[4];
#pragma unroll
        for (int i = 0; i < 4; ++i) af[i]  = *(const short8*)&lA[(wr + i * 16 + qr) * 32 + qh * 8];
#pragma unroll
        for (int i = 0; i < 4; ++i) bfr[i] = *(const short8*)&lB[(wc + i * 16 + qr) * 32 + qh * 8];
#pragma unroll
        for (int mi = 0; mi < 4; ++mi)
#pragma unroll
            for (int ni = 0; ni < 4; ++ni)
                acc[mi][ni] = __builtin_amdgcn_mfma_f32_16x16x32_bf16(af[mi], bfr[ni], acc[mi][ni], 0, 0, 0);
        __syncthreads();
    }

#pragma unroll
    for (int mi = 0; mi < 4; ++mi)
#pragma unroll
        for (int ni = 0; ni < 4; ++ni) {
            const int col = n0 + wc + ni * 16 + qr;
            float bv = bias[col];
            f32x4 a = acc[mi][ni];
#pragma unroll
            for (int j = 0; j < 4; ++j) {
                const int row = m0 + wr + mi * 16 + qh * 4 + j;
                float v = a[j] + bv;
                if (EPI == 2) ((float*)Cp)[(size_t)row * ldc + col] = v;
                else          ((u16*)Cp)[(size_t)row * ldc + col]  = f2bf(v);
            }
        }
}

// ---------------------------------------------------------------- score GEMM
// R6's proven slot-fused 2-barrier structure, widened to BK=64: two 32-k
// panels staged (8 global_load_lds) per barrier pair, 32 MFMA between
// barriers. Halves the stage-drain phases per block vs R6. No manual vmcnt,
// no sched_barrier — compiler schedules within phases (m141 lesson).
// Filter epilogue per slot: LDS-aggregated candidates, one global atomic per
// (block,row) + short coalesced copy.
__global__ __launch_bounds__(256) void gemm_scores(
    const short* __restrict__ A, const short* __restrict__ Bk,
    const float* __restrict__ rn, u32* __restrict__ cnt,
    float2* __restrict__ cand, int cap, float cmul)
{
    __shared__ __align__(16) short lA[2][128 * 32];
    __shared__ __align__(16) short lB[2][128 * 32];
    __shared__ u32    lcnt[128];
    __shared__ float2 lbuf[128][CAPB];

    const int t  = threadIdx.x;
    const int m0 = blockIdx.y << 7, n0 = blockIdx.x << 7;
    const int w  = t >> 6, lane = t & 63;
    const int wr = (w >> 1) << 6, wc = (w & 1) << 6;
    const int qr = lane & 15, qh = lane >> 4;
    const int K  = 256;

    const short* ga0 = A + (size_t)(m0 + (t >> 2)) * K + (t & 3) * 8;
    const short* ga1 = ga0 + (size_t)64 * K;
    const short* gbb = Bk + (size_t)(n0 + (t >> 2)) * K + (t & 3) * 8;
    char* lAb0 = (char*)&lA[0][0] + w * 1024;
    char* lAb1 = (char*)&lA[1][0] + w * 1024;
    char* lBb0 = (char*)&lB[0][0] + w * 1024;
    char* lBb1 = (char*)&lB[1][0] + w * 1024;

    for (int s = 0; s < 4; ++s) {
        const short* gb0 = gbb + (size_t)s * (16384 * 256);
        const short* gb1 = gb0 + (size_t)64 * K;

        f32x4 acc[4][4];
#pragma unroll
        for (int i = 0; i < 4; ++i)
#pragma unroll
            for (int j = 0; j < 4; ++j) acc[i][j] = (f32x4){0.f, 0.f, 0.f, 0.f};

        for (int k0 = 0; k0 < K; k0 += 64) {
            // stage two 32-k panels (8 issues), one drain+barrier
            __builtin_amdgcn_global_load_lds((const AS1 void*)(ga0 + k0),      (AS3 void*)lAb0,          16, 0, 0);
            __builtin_amdgcn_global_load_lds((const AS1 void*)(ga1 + k0),      (AS3 void*)(lAb0 + 4096), 16, 0, 0);
            __builtin_amdgcn_global_load_lds((const AS1 void*)(gb0 + k0),      (AS3 void*)lBb0,          16, 0, 0);
            __builtin_amdgcn_global_load_lds((const AS1 void*)(gb1 + k0),      (AS3 void*)(lBb0 + 4096), 16, 0, 0);
            __builtin_amdgcn_global_load_lds((const AS1 void*)(ga0 + k0 + 32), (AS3 void*)lAb1,          16, 0, 0);
            __builtin_amdgcn_global_load_lds((const AS1 void*)(ga1 + k0 + 32), (AS3 void*)(lAb1 + 4096), 16, 0, 0);
            __builtin_amdgcn_global_load_lds((const AS1 void*)(gb0 + k0 + 32), (AS3 void*)lBb1,          16, 0, 0);
            __builtin_amdgcn_global_load_lds((const AS1 void*)(gb1 + k0 + 32), (AS3 void*)(lBb1 + 4096), 16, 0, 0);
            __syncthreads();
#pragma unroll
            for (int kk = 0; kk < 2; ++kk) {
                short8 af[4], bfr[4];
#pragma unroll
                for (int i = 0; i < 4; ++i) af[i]  = *(const short8*)&lA[kk][(wr + i * 16 + qr) * 32 + qh * 8];
#pragma unroll
                for (int i = 0; i < 4; ++i) bfr[i] = *(const short8*)&lB[kk][(wc + i * 16 + qr) * 32 + qh * 8];
#pragma unroll
                for (int mi = 0; mi < 4; ++mi)
#pragma unroll
                    for (int ni = 0; ni < 4; ++ni)
                        acc[mi][ni] = __builtin_amdgcn_mfma_f32_16x16x32_bf16(af[mi], bfr[ni], acc[mi][ni], 0, 0, 0);
            }
            __syncthreads();
        }

        // ---- filter epilogue for slot s
        u32*    cnts  = cnt  + (size_t)s * 4096 * CSTRIDE;
        float2* cands = cand + (size_t)s * 4096 * cap;

        if (t < 128) lcnt[t] = 0;
        __syncthreads();

#pragma unroll
        for (int mi = 0; mi < 4; ++mi) {
            const int rbase = wr + mi * 16 + qh * 4;   // local row base
            float thrj[4];
#pragma unroll
            for (int j = 0; j < 4; ++j)
                thrj[j] = cmul * rn[m0 + rbase + j];
#pragma unroll
            for (int ni = 0; ni < 4; ++ni) {
                const int col = n0 + wc + ni * 16 + qr;
                f32x4 a = acc[mi][ni];
#pragma unroll
                for (int j = 0; j < 4; ++j) {
                    float v = a[j];
                    if (v > thrj[j]) {
                        const int rl = rbase + j;
                        u32 p = atomicAdd(&lcnt[rl], 1u);
                        if (p < CAPB)
                            lbuf[rl][p] = make_float2(v, __uint_as_float((u32)col));
                    }
                }
            }
        }
        __syncthreads();

        // flush: thread t (<128) owns local row t — one global atomic + copy
        if (t < 128) {
            int c = (int)lcnt[t];
            if (c > CAPB) c = CAPB;
            if (c > 0) {
                const int row = m0 + t;
                u32 base = atomicAdd(&cnts[(size_t)row * CSTRIDE], (u32)c);
                float2* dst = cands + (size_t)row * cap;
                for (int i = 0; i < c; ++i) {
                    u32 p = base + (u32)i;
                    if (p < (u32)cap) dst[p] = lbuf[t][i];
                }
            }
        }
        __syncthreads();   // lbuf free before next slot's filter
    }
}

// ---------------------------------------------------------------- select+gather
// One WAVE per (slot,row). Reads the row's candidate list (~300 f32 entries),
// exact top-32 by 32x wave-argmax with (val desc, idx asc) order — identical
// semantics to jax.lax.top_k on the f32 scores. Softmax, fused weighted gather
// of values + residual.
__global__ __launch_bounds__(256) void k_select(
    const u32* __restrict__ cnt, const float2* __restrict__ cand, int cap,
    const void* __restrict__ vtab,    // value tables, all slots (bf16 or f32)
    const float* __restrict__ res,    // BS x 512
    float* __restrict__ out,          // BS x 4 x 512
    int useBf)
{
    __shared__ float2 cbuf[4][512];
    __shared__ float  topw[4][32];
    __shared__ int    topi[4][32];

    const int t = threadIdx.x;
    const int w = t >> 6, lane = t & 63;
    const int wid = blockIdx.x * 4 + w;          // 0..16383
    const int s   = wid >> 12;                   // slot
    const int row = wid & 4095;                  // batch row
    const int g   = s * 4096 + row;

    int c = (int)cnt[(size_t)g * CSTRIDE];
    if (c > cap) c = cap;
    const float2* cp = cand + (size_t)g * cap;
    for (int i = lane; i < c; i += 64) cbuf[w][i] = cp[i];

    // ---- 32x wave-argmax (val desc, idx asc), wave-synchronous
    for (int k = 0; k < 32; ++k) {
        float bv = -3.0e38f; int bi = 0x7fffffff; int bp = -1;
        for (int i = lane; i < c; i += 64) {
            float2 e = cbuf[w][i];
            float v = e.x; int id = (int)__float_as_uint(e.y);
            if (v > bv || (v == bv && id < bi)) { bv = v; bi = id; bp = i; }
        }
#pragma unroll
        for (int o = 32; o; o >>= 1) {
            float ov = __shfl_xor(bv, o);
            int   oi = __shfl_xor(bi, o);
            int   op = __shfl_xor(bp, o);
            if (ov > bv || (ov == bv && oi < bi)) { bv = ov; bi = oi; bp = op; }
        }
        if (lane == 0) {
            topw[w][k] = bv;
            topi[w][k] = (bi == 0x7fffffff) ? 0 : bi;
            if (bp >= 0) cbuf[w][bp].x = -3.0e38f;   // remove winner
        }
    }

    // ---- softmax over top-32 (lanes 0..31; k=0 holds the max)
    if (lane < 32) {
        float v  = topw[w][lane];
        float mx = topw[w][0];
        float e  = expf(v - mx);
        float sum = e;
#pragma unroll
        for (int o = 16; o; o >>= 1) sum += __shfl_xor(sum, o, 32);
        topw[w][lane] = e / sum;
    }

    // ---- fused gather + residual: lane owns 8 contiguous outputs
    const int v0 = lane * 8;
    float a[8];
    {
        float4 r0v = *(const float4*)(res + (size_t)row * 512 + v0);
        float4 r1v = *(const float4*)(res + (size_t)row * 512 + v0 + 4);
        a[0] = r0v.x; a[1] = r0v.y; a[2] = r0v.z; a[3] = r0v.w;
        a[4] = r1v.x; a[5] = r1v.y; a[6] = r1v.z; a[7] = r1v.w;
    }
    if (useBf) {
        const u16* vt = (const u16*)vtab + (size_t)s * 16384 * 512;
#pragma unroll 8
        for (int k = 0; k < 32; ++k) {
            float w2 = topw[w][k];
            ushort8 u = *(const ushort8*)(vt + (size_t)topi[w][k] * 512 + v0);
#pragma unroll
            for (int i = 0; i < 8; ++i) a[i] += w2 * bf2f(u[i]);
        }
    } else {
        const float* vt = (const float*)vtab + (size_t)s * 16384 * 512;
#pragma unroll 4
        for (int k = 0; k < 32; ++k) {
            float w2 = topw[w][k];
            const float* vp = vt + (size_t)topi[w][k] * 512 + v0;
            float4 u0 = *(const float4*)vp;
            float4 u1 = *(const float4*)(vp + 4);
            a[0] += w2 * u0.x; a[1] += w2 * u0.y; a[2] += w2 * u0.z; a[3] += w2 * u0.w;
            a[4] += w2 * u1.x; a[5] += w2 * u1.y; a[6] += w2 * u1.z; a[7] += w2 * u1.w;
        }
    }
    float* op = out + ((size_t)row * 4 + s) * 512 + v0;
    *(float4*)op       = (float4){a[0], a[1], a[2], a[3]};
    *(float4*)(op + 4) = (float4){a[4], a[5], a[6], a[7]};
}

// ---------------------------------------------------------------- host

extern "C" void kernel_launch(void* const* d_in, const int* in_sizes, int n_in,
                              void* d_out, int out_size, void* d_ws, size_t ws_size,
                              hipStream_t stream)
{
    const float* x    = (const float*)d_in[0];
    const float* Wq   = (const float*)d_in[1];
    const float* bq   = (const float*)d_in[2];
    const float* keys = (const float*)d_in[3];
    const float* vals = (const float*)d_in[4];
    const float* Wr   = (const float*)d_in[5];
    const float* br   = (const float*)d_in[6];
    float* out = (float*)d_out;
    char*  ws  = (char*)d_ws;

    constexpr int BS = 4096, D = 512, KD = 256, VD = 512, S = 4, NK = 16384;

    size_t pos = 0;
    auto take = [&](size_t bytes) -> size_t {
        size_t p = (pos + 255) & ~(size_t)255; pos = p + bytes; return p;
    };
    size_t o_xbf = take((size_t)BS * D * 2);
    size_t o_wqt = take((size_t)KD * D * 2);
    size_t o_wrt = take((size_t)VD * KD * 2);
    size_t o_qbf = take((size_t)BS * KD * 2);
    size_t o_res = take((size_t)BS * VD * 4);
    size_t o_kn  = take((size_t)S * NK * KD * 2);
    size_t o_rn  = take((size_t)BS * 4);
    size_t o_cnt = take((size_t)S * BS * CSTRIDE * 4);   // 64B-padded counters
    size_t core_end = pos;

    // tiers: [vbf?] + candidate capacity / threshold constant
    const size_t vbf_b = (size_t)S * NK * VD * 2;                  // 64 MB
    auto cand_b = [&](int cap) { return (size_t)S * BS * cap * 8; };
    bool use_vbf = false; int cap = 192; float cmul = 2.45f / 16.0f;
    if (core_end + vbf_b + cand_b(512) + 1024 <= ws_size) {
        use_vbf = true;  cap = 512; cmul = 2.1f / 16.0f;
    } else if (core_end + cand_b(512) + 1024 <= ws_size) {
        use_vbf = false; cap = 512; cmul = 2.1f / 16.0f;
    } else if (core_end + cand_b(320) + 1024 <= ws_size) {
        use_vbf = false; cap = 320; cmul = 2.3f / 16.0f;
    }
    size_t o_vbf  = use_vbf ? take(vbf_b) : 0;
    size_t o_cand = take(cand_b(cap));

    // zero per-row candidate counters (graph-capturable memset node)
    hipMemsetAsync(ws + o_cnt, 0, (size_t)S * BS * CSTRIDE * 4, stream);

    // prep
    k_transpose_cast<<<(D * KD + 255) / 256, 256, 0, stream>>>(Wq, (u16*)(ws + o_wqt), D, KD);
    k_transpose_cast<<<(KD * VD + 255) / 256, 256, 0, stream>>>(Wr, (u16*)(ws + o_wrt), KD, VD);
    k_cast8<<<(BS * D) / 2048, 256, 0, stream>>>(x, (u16*)(ws + o_xbf));
    if (use_vbf)
        k_cast8<<<(S * NK * VD) / 2048, 256, 0, stream>>>(vals, (u16*)(ws + o_vbf));
    k_norm_keys<<<(S * NK) / 4, 256, 0, stream>>>(keys, (u16*)(ws + o_kn));

    // q = x @ Wq + bq  (bf16 out)
    gemm_nt<1><<<dim3(KD / 128, BS / 128), 256, 0, stream>>>(
        (const short*)(ws + o_xbf), (const short*)(ws + o_wqt),
        ws + o_qbf, bq, BS, KD, D, KD);
    // row norms of q
    k_rownorm<<<BS / 4, 256, 0, stream>>>((const u16*)(ws + o_qbf), (float*)(ws + o_rn));
    // res = q @ Wr + br  (f32 out)
    gemm_nt<2><<<dim3(VD / 128, BS / 128), 256, 0, stream>>>(
        (const short*)(ws + o_qbf), (const short*)(ws + o_wrt),
        ws + o_res, br, BS, VD, KD, VD);

    // scores: slot-fused single dispatch; epilogue filters into candidate lists
    gemm_scores<<<dim3(NK / 128, BS / 128), 256, 0, stream>>>(
        (const short*)(ws + o_qbf), (const short*)(ws + o_kn),
        (const float*)(ws + o_rn), (u32*)(ws + o_cnt),
        (float2*)(ws + o_cand), cap, cmul);

    // exact top-32 + softmax + gather + residual, all slots in one dispatch
    const void* vtab = use_vbf ? (const void*)(ws + o_vbf) : (const void*)vals;
    k_select<<<(S * BS) / 4, 256, 0, stream>>>(
        (const u32*)(ws + o_cnt), (const float2*)(ws + o_cand), cap,
        vtab, (const float*)(ws + o_res), out, use_vbf ? 1 : 0);
}

// Round 10
// 548.644 us; speedup vs baseline: 1.5602x; 1.0068x over previous
//
#include <hip/hip_runtime.h>

typedef unsigned short u16;
typedef unsigned int   u32;
typedef __attribute__((ext_vector_type(8))) short  short8;
typedef __attribute__((ext_vector_type(8))) u16    ushort8;
typedef __attribute__((ext_vector_type(4))) u16    ushort4v;
typedef __attribute__((ext_vector_type(4))) float  f32x4;

#define AS1 __attribute__((address_space(1)))
#define AS3 __attribute__((address_space(3)))

// counters are padded: one u32 per 64B line (stride 16 u32)
#define CSTRIDE 16
// per-(block,row,slot) LDS candidate list capacity (Poisson(~2.3), P(>16)~1e-11)
#define CAPB 16

__device__ __forceinline__ float bf2f(u16 u) {
    union { u32 i; float f; } x; x.i = ((u32)u) << 16; return x.f;
}
__device__ __forceinline__ u16 f2bf(float f) {
    union { float f; u32 i; } x; x.f = f;
    u32 r = x.i + 0x7fffu + ((x.i >> 16) & 1u);
    return (u16)(r >> 16);
}

// ---------------------------------------------------------------- prep kernels

__global__ __launch_bounds__(256) void k_transpose_cast(
    const float* __restrict__ src, u16* __restrict__ dst, int R, int C)
{
    int i = blockIdx.x * 256 + threadIdx.x;
    if (i >= R * C) return;
    int r = i / C, c = i - r * C;
    dst[(size_t)c * R + r] = f2bf(src[i]);
}

__global__ __launch_bounds__(256) void k_cast8(
    const float* __restrict__ src, u16* __restrict__ dst)
{
    size_t i = ((size_t)blockIdx.x * 256 + threadIdx.x) * 8;
    float4 a = *(const float4*)(src + i);
    float4 b = *(const float4*)(src + i + 4);
    ushort8 o;
    o[0] = f2bf(a.x); o[1] = f2bf(a.y); o[2] = f2bf(a.z); o[3] = f2bf(a.w);
    o[4] = f2bf(b.x); o[5] = f2bf(b.y); o[6] = f2bf(b.z); o[7] = f2bf(b.w);
    *(ushort8*)(dst + i) = o;
}

// one wave per key vector (256 floats); 4 keys per block
__global__ __launch_bounds__(256) void k_norm_keys(
    const float* __restrict__ keys, u16* __restrict__ kn)
{
    int key  = blockIdx.x * 4 + (threadIdx.x >> 6);
    int lane = threadIdx.x & 63;
    const float* kp = keys + (size_t)key * 256 + lane * 4;
    float4 v = *(const float4*)kp;
    float ss = v.x * v.x + v.y * v.y + v.z * v.z + v.w * v.w;
#pragma unroll
    for (int o = 32; o; o >>= 1) ss += __shfl_xor(ss, o);
    float sc = 1.0f / sqrtf(ss);
    ushort4v o4;
    o4[0] = f2bf(v.x * sc); o4[1] = f2bf(v.y * sc);
    o4[2] = f2bf(v.z * sc); o4[3] = f2bf(v.w * sc);
    *(ushort4v*)(kn + (size_t)key * 256 + lane * 4) = o4;
}

// one wave per q row: rn[row] = |q_row|  (from bf16 q)
__global__ __launch_bounds__(256) void k_rownorm(
    const u16* __restrict__ q, float* __restrict__ rn)
{
    int row  = blockIdx.x * 4 + (threadIdx.x >> 6);
    int lane = threadIdx.x & 63;
    ushort4v u = *(const ushort4v*)(q + (size_t)row * 256 + lane * 4);
    float a = bf2f(u[0]), b = bf2f(u[1]), c = bf2f(u[2]), d = bf2f(u[3]);
    float ss = a * a + b * b + c * c + d * d;
#pragma unroll
    for (int o = 32; o; o >>= 1) ss += __shfl_xor(ss, o);
    if (lane == 0) rn[row] = sqrtf(ss);
}

// ---------------------------------------------------------------- bf16 NT GEMM
// C(MxN) = A(MxK) * B(NxK)^T ; A,B bf16 row-major (K contiguous).
// EPI 1: +bias, store bf16. EPI 2: +bias, store f32.
template<int EPI>
__global__ __launch_bounds__(256) void gemm_nt(
    const short* __restrict__ A, const short* __restrict__ B,
    void* __restrict__ Cp, const float* __restrict__ bias,
    int M, int N, int K, int ldc)
{
    __shared__ __align__(16) short lA[128 * 32];
    __shared__ __align__(16) short lB[128 * 32];
    const int t  = threadIdx.x;
    const int m0 = blockIdx.y << 7, n0 = blockIdx.x << 7;
    const int w  = t >> 6, lane = t & 63;
    const int wr = (w >> 1) << 6, wc = (w & 1) << 6;
    const int qr = lane & 15, qh = lane >> 4;

    f32x4 acc[4][4];
#pragma unroll
    for (int i = 0; i < 4; ++i)
#pragma unroll
        for (int j = 0; j < 4; ++j) acc[i][j] = (f32x4){0.f, 0.f, 0.f, 0.f};

    const short* ga0 = A + (size_t)(m0 + (t >> 2)) * K + (t & 3) * 8;
    const short* ga1 = ga0 + (size_t)64 * K;
    const short* gb0 = B + (size_t)(n0 + (t >> 2)) * K + (t & 3) * 8;
    const short* gb1 = gb0 + (size_t)64 * K;
    char* lAb = (char*)lA + w * 1024;
    char* lBb = (char*)lB + w * 1024;

    for (int k0 = 0; k0 < K; k0 += 32) {
        __builtin_amdgcn_global_load_lds((const AS1 void*)(ga0 + k0), (AS3 void*)lAb,          16, 0, 0);
        __builtin_amdgcn_global_load_lds((const AS1 void*)(ga1 + k0), (AS3 void*)(lAb + 4096), 16, 0, 0);
        __builtin_amdgcn_global_load_lds((const AS1 void*)(gb0 + k0), (AS3 void*)lBb,          16, 0, 0);
        __builtin_amdgcn_global_load_lds((const AS1 void*)(gb1 + k0), (AS3 void*)(lBb + 4096), 16, 0, 0);
        __syncthreads();
        short8 af[4], bfr[4];
#pragma unroll
        for (int i = 0; i < 4; ++i) af[i]  = *(const short8*)&lA[(wr + i * 16 + qr) * 32 + qh * 8];
#pragma unroll
        for (int i = 0; i < 4; ++i) bfr[i] = *(const short8*)&lB[(wc + i * 16 + qr) * 32 + qh * 8];
#pragma unroll
        for (int mi = 0; mi < 4; ++mi)
#pragma unroll
            for (int ni = 0; ni < 4; ++ni)
                acc[mi][ni] = __builtin_amdgcn_mfma_f32_16x16x32_bf16(af[mi], bfr[ni], acc[mi][ni], 0, 0, 0);
        __syncthreads();
    }

#pragma unroll
    for (int mi = 0; mi < 4; ++mi)
#pragma unroll
        for (int ni = 0; ni < 4; ++ni) {
            const int col = n0 + wc + ni * 16 + qr;
            float bv = bias[col];
            f32x4 a = acc[mi][ni];
#pragma unroll
            for (int j = 0; j < 4; ++j) {
                const int row = m0 + wr + mi * 16 + qh * 4 + j;
                float v = a[j] + bv;
                if (EPI == 2) ((float*)Cp)[(size_t)row * ldc + col] = v;
                else          ((u16*)Cp)[(size_t)row * ldc + col]  = f2bf(v);
            }
        }
}

// ---------------------------------------------------------------- score GEMM
// R9 structure (slot-fused, BK=64, 2-barrier loop) + XCD-chunked block remap:
// consecutive launch IDs round-robin across 8 XCDs, so give each XCD a
// contiguous chunk of 16 n-columns; all 32 m-blocks of a column land on ONE
// XCD and its B-panels (keys) are served from that XCD's L2 after the first
// fetch, instead of L3/HBM for every block. Bijective: 4096 = 8*16*32.
__global__ __launch_bounds__(256) void gemm_scores(
    const short* __restrict__ A, const short* __restrict__ Bk,
    const float* __restrict__ rn, u32* __restrict__ cnt,
    float2* __restrict__ cand, int cap, float cmul)
{
    __shared__ __align__(16) short lA[2][128 * 32];
    __shared__ __align__(16) short lB[2][128 * 32];
    __shared__ u32    lcnt[128];
    __shared__ float2 lbuf[128][CAPB];

    const int t  = threadIdx.x;
    // XCD-chunked remap (launch-order id: x fastest)
    const int f   = blockIdx.y * gridDim.x + blockIdx.x;
    const int xcd = f & 7, loc = f >> 3;
    const int col = xcd * 16 + (loc >> 5);     // 0..127  (16 cols per XCD)
    const int row = loc & 31;                  // 0..31
    const int m0 = row << 7, n0 = col << 7;
    const int w  = t >> 6, lane = t & 63;
    const int wr = (w >> 1) << 6, wc = (w & 1) << 6;
    const int qr = lane & 15, qh = lane >> 4;
    const int K  = 256;

    const short* ga0 = A + (size_t)(m0 + (t >> 2)) * K + (t & 3) * 8;
    const short* ga1 = ga0 + (size_t)64 * K;
    const short* gbb = Bk + (size_t)(n0 + (t >> 2)) * K + (t & 3) * 8;
    char* lAb0 = (char*)&lA[0][0] + w * 1024;
    char* lAb1 = (char*)&lA[1][0] + w * 1024;
    char* lBb0 = (char*)&lB[0][0] + w * 1024;
    char* lBb1 = (char*)&lB[1][0] + w * 1024;

    for (int s = 0; s < 4; ++s) {
        const short* gb0 = gbb + (size_t)s * (16384 * 256);
        const short* gb1 = gb0 + (size_t)64 * K;

        f32x4 acc[4][4];
#pragma unroll
        for (int i = 0; i < 4; ++i)
#pragma unroll
            for (int j = 0; j < 4; ++j) acc[i][j] = (f32x4){0.f, 0.f, 0.f, 0.f};

        for (int k0 = 0; k0 < K; k0 += 64) {
            // stage two 32-k panels (8 issues), one drain+barrier
            __builtin_amdgcn_global_load_lds((const AS1 void*)(ga0 + k0),      (AS3 void*)lAb0,          16, 0, 0);
            __builtin_amdgcn_global_load_lds((const AS1 void*)(ga1 + k0),      (AS3 void*)(lAb0 + 4096), 16, 0, 0);
            __builtin_amdgcn_global_load_lds((const AS1 void*)(gb0 + k0),      (AS3 void*)lBb0,          16, 0, 0);
            __builtin_amdgcn_global_load_lds((const AS1 void*)(gb1 + k0),      (AS3 void*)(lBb0 + 4096), 16, 0, 0);
            __builtin_amdgcn_global_load_lds((const AS1 void*)(ga0 + k0 + 32), (AS3 void*)lAb1,          16, 0, 0);
            __builtin_amdgcn_global_load_lds((const AS1 void*)(ga1 + k0 + 32), (AS3 void*)(lAb1 + 4096), 16, 0, 0);
            __builtin_amdgcn_global_load_lds((const AS1 void*)(gb0 + k0 + 32), (AS3 void*)lBb1,          16, 0, 0);
            __builtin_amdgcn_global_load_lds((const AS1 void*)(gb1 + k0 + 32), (AS3 void*)(lBb1 + 4096), 16, 0, 0);
            __syncthreads();
#pragma unroll
            for (int kk = 0; kk < 2; ++kk) {
                short8 af[4], bfr[4];
#pragma unroll
                for (int i = 0; i < 4; ++i) af[i]  = *(const short8*)&lA[kk][(wr + i * 16 + qr) * 32 + qh * 8];
#pragma unroll
                for (int i = 0; i < 4; ++i) bfr[i] = *(const short8*)&lB[kk][(wc + i * 16 + qr) * 32 + qh * 8];
#pragma unroll
                for (int mi = 0; mi < 4; ++mi)
#pragma unroll
                    for (int ni = 0; ni < 4; ++ni)
                        acc[mi][ni] = __builtin_amdgcn_mfma_f32_16x16x32_bf16(af[mi], bfr[ni], acc[mi][ni], 0, 0, 0);
            }
            __syncthreads();
        }

        // ---- filter epilogue for slot s
        u32*    cnts  = cnt  + (size_t)s * 4096 * CSTRIDE;
        float2* cands = cand + (size_t)s * 4096 * cap;

        if (t < 128) lcnt[t] = 0;
        __syncthreads();

#pragma unroll
        for (int mi = 0; mi < 4; ++mi) {
            const int rbase = wr + mi * 16 + qh * 4;   // local row base
            float thrj[4];
#pragma unroll
            for (int j = 0; j < 4; ++j)
                thrj[j] = cmul * rn[m0 + rbase + j];
#pragma unroll
            for (int ni = 0; ni < 4; ++ni) {
                const int colI = n0 + wc + ni * 16 + qr;
                f32x4 a = acc[mi][ni];
#pragma unroll
                for (int j = 0; j < 4; ++j) {
                    float v = a[j];
                    if (v > thrj[j]) {
                        const int rl = rbase + j;
                        u32 p = atomicAdd(&lcnt[rl], 1u);
                        if (p < CAPB)
                            lbuf[rl][p] = make_float2(v, __uint_as_float((u32)colI));
                    }
                }
            }
        }
        __syncthreads();

        // flush: thread t (<128) owns local row t — one global atomic + copy
        if (t < 128) {
            int c = (int)lcnt[t];
            if (c > CAPB) c = CAPB;
            if (c > 0) {
                const int rowG = m0 + t;
                u32 base = atomicAdd(&cnts[(size_t)rowG * CSTRIDE], (u32)c);
                float2* dst = cands + (size_t)rowG * cap;
                for (int i = 0; i < c; ++i) {
                    u32 p = base + (u32)i;
                    if (p < (u32)cap) dst[p] = lbuf[t][i];
                }
            }
        }
        __syncthreads();   // lbuf free before next slot's filter
    }
}

// ---------------------------------------------------------------- select+gather
// One WAVE per (slot,row). Reads the row's candidate list (~300 f32 entries),
// exact top-32 by 32x wave-argmax with (val desc, idx asc) order — identical
// semantics to jax.lax.top_k on the f32 scores. Softmax, fused weighted gather
// of values + residual.
__global__ __launch_bounds__(256) void k_select(
    const u32* __restrict__ cnt, const float2* __restrict__ cand, int cap,
    const void* __restrict__ vtab,    // value tables, all slots (bf16 or f32)
    const float* __restrict__ res,    // BS x 512
    float* __restrict__ out,          // BS x 4 x 512
    int useBf)
{
    __shared__ float2 cbuf[4][512];
    __shared__ float  topw[4][32];
    __shared__ int    topi[4][32];

    const int t = threadIdx.x;
    const int w = t >> 6, lane = t & 63;
    const int wid = blockIdx.x * 4 + w;          // 0..16383
    const int s   = wid >> 12;                   // slot
    const int row = wid & 4095;                  // batch row
    const int g   = s * 4096 + row;

    int c = (int)cnt[(size_t)g * CSTRIDE];
    if (c > cap) c = cap;
    const float2* cp = cand + (size_t)g * cap;
    for (int i = lane; i < c; i += 64) cbuf[w][i] = cp[i];

    // ---- 32x wave-argmax (val desc, idx asc), wave-synchronous
    for (int k = 0; k < 32; ++k) {
        float bv = -3.0e38f; int bi = 0x7fffffff; int bp = -1;
        for (int i = lane; i < c; i += 64) {
            float2 e = cbuf[w][i];
            float v = e.x; int id = (int)__float_as_uint(e.y);
            if (v > bv || (v == bv && id < bi)) { bv = v; bi = id; bp = i; }
        }
#pragma unroll
        for (int o = 32; o; o >>= 1) {
            float ov = __shfl_xor(bv, o);
            int   oi = __shfl_xor(bi, o);
            int   op = __shfl_xor(bp, o);
            if (ov > bv || (ov == bv && oi < bi)) { bv = ov; bi = oi; bp = op; }
        }
        if (lane == 0) {
            topw[w][k] = bv;
            topi[w][k] = (bi == 0x7fffffff) ? 0 : bi;
            if (bp >= 0) cbuf[w][bp].x = -3.0e38f;   // remove winner
        }
    }

    // ---- softmax over top-32 (lanes 0..31; k=0 holds the max)
    if (lane < 32) {
        float v  = topw[w][lane];
        float mx = topw[w][0];
        float e  = expf(v - mx);
        float sum = e;
#pragma unroll
        for (int o = 16; o; o >>= 1) sum += __shfl_xor(sum, o, 32);
        topw[w][lane] = e / sum;
    }

    // ---- fused gather + residual: lane owns 8 contiguous outputs
    const int v0 = lane * 8;
    float a[8];
    {
        float4 r0v = *(const float4*)(res + (size_t)row * 512 + v0);
        float4 r1v = *(const float4*)(res + (size_t)row * 512 + v0 + 4);
        a[0] = r0v.x; a[1] = r0v.y; a[2] = r0v.z; a[3] = r0v.w;
        a[4] = r1v.x; a[5] = r1v.y; a[6] = r1v.z; a[7] = r1v.w;
    }
    if (useBf) {
        const u16* vt = (const u16*)vtab + (size_t)s * 16384 * 512;
#pragma unroll 8
        for (int k = 0; k < 32; ++k) {
            float w2 = topw[w][k];
            ushort8 u = *(const ushort8*)(vt + (size_t)topi[w][k] * 512 + v0);
#pragma unroll
            for (int i = 0; i < 8; ++i) a[i] += w2 * bf2f(u[i]);
        }
    } else {
        const float* vt = (const float*)vtab + (size_t)s * 16384 * 512;
#pragma unroll 4
        for (int k = 0; k < 32; ++k) {
            float w2 = topw[w][k];
            const float* vp = vt + (size_t)topi[w][k] * 512 + v0;
            float4 u0 = *(const float4*)vp;
            float4 u1 = *(const float4*)(vp + 4);
            a[0] += w2 * u0.x; a[1] += w2 * u0.y; a[2] += w2 * u0.z; a[3] += w2 * u0.w;
            a[4] += w2 * u1.x; a[5] += w2 * u1.y; a[6] += w2 * u1.z; a[7] += w2 * u1.w;
        }
    }
    float* op = out + ((size_t)row * 4 + s) * 512 + v0;
    *(float4*)op       = (float4){a[0], a[1], a[2], a[3]};
    *(float4*)(op + 4) = (float4){a[4], a[5], a[6], a[7]};
}

// ---------------------------------------------------------------- host

extern "C" void kernel_launch(void* const* d_in, const int* in_sizes, int n_in,
                              void* d_out, int out_size, void* d_ws, size_t ws_size,
                              hipStream_t stream)
{
    const float* x    = (const float*)d_in[0];
    const float* Wq   = (const float*)d_in[1];
    const float* bq   = (const float*)d_in[2];
    const float* keys = (const float*)d_in[3];
    const float* vals = (const float*)d_in[4];
    const float* Wr   = (const float*)d_in[5];
    const float* br   = (const float*)d_in[6];
    float* out = (float*)d_out;
    char*  ws  = (char*)d_ws;

    constexpr int BS = 4096, D = 512, KD = 256, VD = 512, S = 4, NK = 16384;

    size_t pos = 0;
    auto take = [&](size_t bytes) -> size_t {
        size_t p = (pos + 255) & ~(size_t)255; pos = p + bytes; return p;
    };
    size_t o_xbf = take((size_t)BS * D * 2);
    size_t o_wqt = take((size_t)KD * D * 2);
    size_t o_wrt = take((size_t)VD * KD * 2);
    size_t o_qbf = take((size_t)BS * KD * 2);
    size_t o_res = take((size_t)BS * VD * 4);
    size_t o_kn  = take((size_t)S * NK * KD * 2);
    size_t o_rn  = take((size_t)BS * 4);
    size_t o_cnt = take((size_t)S * BS * CSTRIDE * 4);   // 64B-padded counters
    size_t core_end = pos;

    // tiers: [vbf?] + candidate capacity / threshold constant
    const size_t vbf_b = (size_t)S * NK * VD * 2;                  // 64 MB
    auto cand_b = [&](int cap) { return (size_t)S * BS * cap * 8; };
    bool use_vbf = false; int cap = 192; float cmul = 2.45f / 16.0f;
    if (core_end + vbf_b + cand_b(512) + 1024 <= ws_size) {
        use_vbf = true;  cap = 512; cmul = 2.1f / 16.0f;
    } else if (core_end + cand_b(512) + 1024 <= ws_size) {
        use_vbf = false; cap = 512; cmul = 2.1f / 16.0f;
    } else if (core_end + cand_b(320) + 1024 <= ws_size) {
        use_vbf = false; cap = 320; cmul = 2.3f / 16.0f;
    }
    size_t o_vbf  = use_vbf ? take(vbf_b) : 0;
    size_t o_cand = take(cand_b(cap));

    // zero per-row candidate counters (graph-capturable memset node)
    hipMemsetAsync(ws + o_cnt, 0, (size_t)S * BS * CSTRIDE * 4, stream);

    // prep
    k_transpose_cast<<<(D * KD + 255) / 256, 256, 0, stream>>>(Wq, (u16*)(ws + o_wqt), D, KD);
    k_transpose_cast<<<(KD * VD + 255) / 256, 256, 0, stream>>>(Wr, (u16*)(ws + o_wrt), KD, VD);
    k_cast8<<<(BS * D) / 2048, 256, 0, stream>>>(x, (u16*)(ws + o_xbf));
    if (use_vbf)
        k_cast8<<<(S * NK * VD) / 2048, 256, 0, stream>>>(vals, (u16*)(ws + o_vbf));
    k_norm_keys<<<(S * NK) / 4, 256, 0, stream>>>(keys, (u16*)(ws + o_kn));

    // q = x @ Wq + bq  (bf16 out)
    gemm_nt<1><<<dim3(KD / 128, BS / 128), 256, 0, stream>>>(
        (const short*)(ws + o_xbf), (const short*)(ws + o_wqt),
        ws + o_qbf, bq, BS, KD, D, KD);
    // row norms of q
    k_rownorm<<<BS / 4, 256, 0, stream>>>((const u16*)(ws + o_qbf), (float*)(ws + o_rn));
    // res = q @ Wr + br  (f32 out)
    gemm_nt<2><<<dim3(VD / 128, BS / 128), 256, 0, stream>>>(
        (const short*)(ws + o_qbf), (const short*)(ws + o_wrt),
        ws + o_res, br, BS, VD, KD, VD);

    // scores: slot-fused single dispatch with XCD-chunked remap
    gemm_scores<<<dim3(NK / 128, BS / 128), 256, 0, stream>>>(
        (const short*)(ws + o_qbf), (const short*)(ws + o_kn),
        (const float*)(ws + o_rn), (u32*)(ws + o_cnt),
        (float2*)(ws + o_cand), cap, cmul);

    // exact top-32 + softmax + gather + residual, all slots in one dispatch
    const void* vtab = use_vbf ? (const void*)(ws + o_vbf) : (const void*)vals;
    k_select<<<(S * BS) / 4, 256, 0, stream>>>(
        (const u32*)(ws + o_cnt), (const float2*)(ws + o_cand), cap,
        vtab, (const float*)(ws + o_res), out, use_vbf ? 1 : 0);
}